// Round 16
// baseline (700.292 us; speedup 1.0000x reference)
//
#include <hip/hip_runtime.h>
#include <hip/hip_bf16.h>
#include <stdint.h>

#define NCOARSE 16384
#define NFINE   65536
#define NEDGE   393216

typedef __bf16 bf16;
typedef bf16 bf16x8 __attribute__((ext_vector_type(8)));
typedef bf16 bf16x4 __attribute__((ext_vector_type(4)));
typedef float f32x4 __attribute__((ext_vector_type(4)));

__device__ __forceinline__ float selu_f(float x) {
    return x > 0.f ? 1.0507009873554805f * x
                   : 1.7580993408473766f * (__expf(x) - 1.f);
}

__device__ __forceinline__ bf16x8 cvt8(f32x4 lo, f32x4 hi) {
    bf16x8 r;
    r[0] = (bf16)lo[0]; r[1] = (bf16)lo[1]; r[2] = (bf16)lo[2]; r[3] = (bf16)lo[3];
    r[4] = (bf16)hi[0]; r[5] = (bf16)hi[1]; r[6] = (bf16)hi[2]; r[7] = (bf16)hi[3];
    return r;
}

// ---------------------------------------------------------------------------
// Weight prep: seg-major bf16 layout  w[seg][128 n][32 k]  (seg = k/32).
// Region offsets (elems): uw1=0, uw2=16384, ew1=32768(+l*49152),
//   ew2=131072(+l*16384), nw1=163840(+l*32768), nw2=229376(+l*16384)
// ---------------------------------------------------------------------------
__global__ void prep_weights(const float* __restrict__ uw1, const float* __restrict__ uw2,
                             const float* __restrict__ ew1, const float* __restrict__ ew2,
                             const float* __restrict__ nw1, const float* __restrict__ nw2,
                             bf16* __restrict__ wb)
{
    int i = blockIdx.x * 256 + threadIdx.x;   // 0..262143, exact
    float v;
    if (i < 16384) {                    // unpool_w1 [128k][128n]
        int j = i; int k = (j >> 12) * 32 + (j & 31), n = (j & 4095) >> 5;
        v = uw1[k * 128 + n];
    } else if (i < 32768) {             // unpool_w2
        int j = i - 16384; int k = (j >> 12) * 32 + (j & 31), n = (j & 4095) >> 5;
        v = uw2[k * 128 + n];
    } else if (i < 131072) {            // edge_w1 [2][384k][128n]
        int j = i - 32768; int l = j / 49152; j -= l * 49152;
        int k = (j >> 12) * 32 + (j & 31), n = (j & 4095) >> 5;
        v = ew1[l * 49152 + k * 128 + n];
    } else if (i < 163840) {            // edge_w2 [2][128][128]
        int j = i - 131072; int l = j >> 14; j &= 16383;
        int k = (j >> 12) * 32 + (j & 31), n = (j & 4095) >> 5;
        v = ew2[l * 16384 + k * 128 + n];
    } else if (i < 229376) {            // node_w1 [2][256k][128n]
        int j = i - 163840; int l = j >> 15; j &= 32767;
        int k = (j >> 12) * 32 + (j & 31), n = (j & 4095) >> 5;
        v = nw1[l * 32768 + k * 128 + n];
    } else {                            // node_w2 [2][128][128]
        int j = i - 229376; int l = j >> 14; j &= 16383;
        int k = (j >> 12) * 32 + (j & 31), n = (j & 4095) >> 5;
        v = nw2[l * 16384 + k * 128 + n];
    }
    wb[i] = (bf16)v;
}

// ---------------------------------------------------------------------------
// CSR build (feeds ONLY the agg kernel).
// ---------------------------------------------------------------------------
__global__ void hist_kernel(const int* __restrict__ ei, int* __restrict__ cnt) {
    int e = blockIdx.x * 256 + threadIdx.x;
    if (e < NEDGE) atomicAdd(&cnt[ei[NEDGE + e]], 1);
}

__global__ __launch_bounds__(1024)
void scan_kernel(const int* __restrict__ cnt, int* __restrict__ rowptr,
                 int* __restrict__ cursor) {
    __shared__ int part[1024];
    const int t = threadIdx.x;
    const int base = t * 64;
    int s = 0;
    for (int i = 0; i < 64; ++i) s += cnt[base + i];
    part[t] = s;
    __syncthreads();
    for (int off = 1; off < 1024; off <<= 1) {
        int v = (t >= off) ? part[t - off] : 0;
        __syncthreads();
        part[t] += v;
        __syncthreads();
    }
    int run = part[t] - s;
    for (int i = 0; i < 64; ++i) {
        int c = cnt[base + i];
        rowptr[base + i] = run;
        cursor[base + i] = run;
        run += c;
    }
    if (t == 1023) rowptr[65536] = run;
}

__global__ void scatter_kernel(const int* __restrict__ ei, int* __restrict__ cursor,
                               int* __restrict__ perm) {
    int e = blockIdx.x * 256 + threadIdx.x;
    if (e < NEDGE) {
        int r = ei[NEDGE + e];
        int p = atomicAdd(&cursor[r], 1);
        perm[p] = e;
    }
}

__global__ __launch_bounds__(256)
void agg_kernel(const bf16* __restrict__ e, const int* __restrict__ rowptr,
                const int* __restrict__ perm, bf16* __restrict__ agg) {
    int t = blockIdx.x * 256 + threadIdx.x;     // 524288 total
    int node = t >> 3, c0 = (t & 7) * 16;
    int s = rowptr[node], en = rowptr[node + 1];
    float acc[16];
    #pragma unroll
    for (int k = 0; k < 16; ++k) acc[k] = 0.f;
    for (int j = s; j < en; ++j) {
        size_t ed = (size_t)perm[j];
        bf16x8 x0 = *(const bf16x8*)(e + ed * 128 + c0);
        bf16x8 x1 = *(const bf16x8*)(e + ed * 128 + c0 + 8);
        #pragma unroll
        for (int k = 0; k < 8; ++k) { acc[k] += (float)x0[k]; acc[8 + k] += (float)x1[k]; }
    }
    bf16x8 o0, o1;
    #pragma unroll
    for (int k = 0; k < 8; ++k) { o0[k] = (bf16)acc[k]; o1[k] = (bf16)acc[8 + k]; }
    *(bf16x8*)(agg + (size_t)node * 128 + c0) = o0;
    *(bf16x8*)(agg + (size_t)node * 128 + c0 + 8) = o1;
}

// ---------------------------------------------------------------------------
// Edge kernel (r12 pair-staging structure, MULTI-TILE): each block processes
// 6 tiles of 128 edges (grid 512 = 2 blocks/CU, ONE round). Next tile's
// gathers are software-pipelined into the current tile's dead registers:
// indices @p1, e-frags @p2, v_s @p4, v_r @p6; weights re-staged to pair0 @p7.
// Amortizes the ~40K-cycle fixed per-block cost over 6 tiles.
// ---------------------------------------------------------------------------
#define STAGE_LOAD2(wp0, wp1) do { \
    st0 = *(const bf16x8*)((wp0) + tid * 8); \
    st1 = *(const bf16x8*)((wp0) + 2048 + tid * 8); \
    st2 = *(const bf16x8*)((wp1) + tid * 8); \
    st3 = *(const bf16x8*)((wp1) + 2048 + tid * 8); } while (0)
#define STAGE_WRITE2(buf) do { \
    *(bf16x8*)&(buf)[0][tid >> 2][(tid & 3) * 8] = st0; \
    *(bf16x8*)&(buf)[0][(tid + 256) >> 2][(tid & 3) * 8] = st1; \
    *(bf16x8*)&(buf)[1][tid >> 2][(tid & 3) * 8] = st2; \
    *(bf16x8*)&(buf)[1][(tid + 256) >> 2][(tid & 3) * 8] = st3; } while (0)

template<bool EF32>
__global__ __launch_bounds__(256, 2)
void edge_kernel(const void* __restrict__ e_in_v,   // fp32 e_skip (L0) or bf16 e (L1)
                 bf16* __restrict__ e_out,
                 const bf16* __restrict__ v_bf,
                 const int* __restrict__ ei,        // [2][NEDGE]
                 const bf16* __restrict__ w1s,      // seg-major [12][128][32]
                 const float* __restrict__ b1,
                 const bf16* __restrict__ w2s,      // seg-major [4][128][32]
                 const float* __restrict__ b2)
{
    const int tid = threadIdx.x;
    const int wv = tid >> 6, lane = tid & 63;
    const int lr = lane & 15, g = lane >> 4;

    __shared__ bf16 wl[2][2][128][40];         // 40,960 B (dbuf x segpair)
    __shared__ bf16 hid_all[4][32][136];       // 34,816 B
    bf16 (*hid)[136] = hid_all[wv];

    const float* e_f32 = (const float*)e_in_v;
    const bf16*  e_b16 = (const bf16*)e_in_v;

    int row0, row1;
    {
        const int base = blockIdx.x * 768 + wv * 32;     // tile 0 of this block
        row0 = base + lr; row1 = base + 16 + lr;
    }
    {
        // prologue gathers for tile 0
        int s0 = ei[row0], s1 = ei[row1];
        int r0 = ei[NEDGE + row0], r1 = ei[NEDGE + row1];
        // fallthrough into shared decl below
        // (loads issued after array decls)
        // NOTE: handled right below
        (void)s0; (void)s1; (void)r0; (void)r1;
    }

    bf16x8 be[4][2], bs[4][2], br[4][2];
    {
        int s0 = ei[row0], s1 = ei[row1];
        int r0 = ei[NEDGE + row0], r1 = ei[NEDGE + row1];
        #pragma unroll
        for (int ks = 0; ks < 4; ++ks) {
            bs[ks][0] = *(const bf16x8*)(v_bf + (size_t)s0 * 128 + ks * 32 + g * 8);
            bs[ks][1] = *(const bf16x8*)(v_bf + (size_t)s1 * 128 + ks * 32 + g * 8);
            br[ks][0] = *(const bf16x8*)(v_bf + (size_t)r0 * 128 + ks * 32 + g * 8);
            br[ks][1] = *(const bf16x8*)(v_bf + (size_t)r1 * 128 + ks * 32 + g * 8);
        }
        if (EF32) {
            #pragma unroll
            for (int ks = 0; ks < 4; ++ks) {
                const float* p0 = e_f32 + (size_t)row0 * 128 + ks * 32 + g * 8;
                const float* p1 = e_f32 + (size_t)row1 * 128 + ks * 32 + g * 8;
                be[ks][0] = cvt8(*(const f32x4*)p0, *(const f32x4*)(p0 + 4));
                be[ks][1] = cvt8(*(const f32x4*)p1, *(const f32x4*)(p1 + 4));
            }
        } else {
            #pragma unroll
            for (int ks = 0; ks < 4; ++ks) {
                be[ks][0] = *(const bf16x8*)(e_b16 + (size_t)row0 * 128 + ks * 32 + g * 8);
                be[ks][1] = *(const bf16x8*)(e_b16 + (size_t)row1 * 128 + ks * 32 + g * 8);
            }
        }
    }

    // ---- stage seg pair {0,1} ----
    bf16x8 st0, st1, st2, st3;
    STAGE_LOAD2(w1s, w1s + 4096);
    STAGE_WRITE2(wl[0]);
    __syncthreads();

    #pragma clang loop unroll(disable)
    for (int t = 0; t < 6; ++t) {
        const bool more = (t < 5);
        int rowN0 = 0, rowN1 = 0, sN0 = 0, sN1 = 0, rN0 = 0, rN1 = 0;

        f32x4 acc1[8][2], acc2[8][2];
        #pragma unroll
        for (int oc = 0; oc < 8; ++oc) {
            f32x4 z = {0.f, 0.f, 0.f, 0.f};
            acc1[oc][0] = z; acc1[oc][1] = z;
        }

        #pragma unroll
        for (int p = 0; p < 8; ++p) {
            const int cur = p & 1;
            if (p < 7) {
                const int s0n = 2 * p + 2, s1n = 2 * p + 3;
                const bf16* wp0 = (s0n < 12) ? w1s + (size_t)s0n * 4096 : w2s + (size_t)(s0n - 12) * 4096;
                const bf16* wp1 = (s1n < 12) ? w1s + (size_t)s1n * 4096 : w2s + (size_t)(s1n - 12) * 4096;
                STAGE_LOAD2(wp0, wp1);
            } else if (more) {
                STAGE_LOAD2(w1s, w1s + 4096);   // next tile's pair {0,1}
            }
            if (p == 1 && more) {               // next-tile indices
                const int base = blockIdx.x * 768 + (t + 1) * 128 + wv * 32;
                rowN0 = base + lr; rowN1 = base + 16 + lr;
                sN0 = ei[rowN0]; sN1 = ei[rowN1];
                rN0 = ei[NEDGE + rowN0]; rN1 = ei[NEDGE + rowN1];
            }
            // A-fragments for both segs of the pair
            bf16x8 a0[8], a1[8];
            #pragma unroll
            for (int oc = 0; oc < 8; ++oc) {
                a0[oc] = *(const bf16x8*)&wl[cur][0][oc * 16 + lr][g * 8];
                a1[oc] = *(const bf16x8*)&wl[cur][1][oc * 16 + lr][g * 8];
            }

            if (p < 6) {
                const int sg0 = 2 * p, sg1 = 2 * p + 1;
                bf16x8 b00 = (sg0 < 4) ? be[sg0][0] : (sg0 < 8) ? bs[sg0 - 4][0] : br[sg0 - 8][0];
                bf16x8 b01 = (sg0 < 4) ? be[sg0][1] : (sg0 < 8) ? bs[sg0 - 4][1] : br[sg0 - 8][1];
                bf16x8 b10 = (sg1 < 4) ? be[sg1][0] : (sg1 < 8) ? bs[sg1 - 4][0] : br[sg1 - 8][0];
                bf16x8 b11 = (sg1 < 4) ? be[sg1][1] : (sg1 < 8) ? bs[sg1 - 4][1] : br[sg1 - 8][1];
                #pragma unroll
                for (int oc = 0; oc < 8; ++oc) {
                    acc1[oc][0] = __builtin_amdgcn_mfma_f32_16x16x32_bf16(a0[oc], b00, acc1[oc][0], 0, 0, 0);
                    acc1[oc][1] = __builtin_amdgcn_mfma_f32_16x16x32_bf16(a0[oc], b01, acc1[oc][1], 0, 0, 0);
                }
                #pragma unroll
                for (int oc = 0; oc < 8; ++oc) {
                    acc1[oc][0] = __builtin_amdgcn_mfma_f32_16x16x32_bf16(a1[oc], b10, acc1[oc][0], 0, 0, 0);
                    acc1[oc][1] = __builtin_amdgcn_mfma_f32_16x16x32_bf16(a1[oc], b11, acc1[oc][1], 0, 0, 0);
                }
            } else {
                if (p == 6) {
                    #pragma unroll
                    for (int oc = 0; oc < 8; ++oc) {
                        f32x4 z = {0.f, 0.f, 0.f, 0.f};
                        acc2[oc][0] = z; acc2[oc][1] = z;
                    }
                }
                const int k2 = 2 * (p - 6);
                bf16x8 h00 = *(const bf16x8*)&hid[lr][k2 * 32 + g * 8];
                bf16x8 h01 = *(const bf16x8*)&hid[16 + lr][k2 * 32 + g * 8];
                bf16x8 h10 = *(const bf16x8*)&hid[lr][(k2 + 1) * 32 + g * 8];
                bf16x8 h11 = *(const bf16x8*)&hid[16 + lr][(k2 + 1) * 32 + g * 8];
                #pragma unroll
                for (int oc = 0; oc < 8; ++oc) {
                    acc2[oc][0] = __builtin_amdgcn_mfma_f32_16x16x32_bf16(a0[oc], h00, acc2[oc][0], 0, 0, 0);
                    acc2[oc][1] = __builtin_amdgcn_mfma_f32_16x16x32_bf16(a0[oc], h01, acc2[oc][1], 0, 0, 0);
                }
                #pragma unroll
                for (int oc = 0; oc < 8; ++oc) {
                    acc2[oc][0] = __builtin_amdgcn_mfma_f32_16x16x32_bf16(a1[oc], h10, acc2[oc][0], 0, 0, 0);
                    acc2[oc][1] = __builtin_amdgcn_mfma_f32_16x16x32_bf16(a1[oc], h11, acc2[oc][1], 0, 0, 0);
                }
            }
            if (p == 5) {  // epilogue1: selu -> hid (both m-tiles)
                #pragma unroll
                for (int mt = 0; mt < 2; ++mt)
                    #pragma unroll
                    for (int oc = 0; oc < 8; ++oc) {
                        const int col = oc * 16 + g * 4;
                        f32x4 bv = *(const f32x4*)(b1 + col);
                        bf16x4 h;
                        #pragma unroll
                        for (int j = 0; j < 4; ++j)
                            h[j] = (bf16)selu_f(acc1[oc][mt][j] + bv[j]);
                        *(bf16x4*)&hid[mt * 16 + lr][col] = h;
                    }
            }
            // ---- next-tile gathers, spread over dead register slots ----
            if (p == 2 && more) {               // be dead after p==1
                if (EF32) {
                    #pragma unroll
                    for (int ks = 0; ks < 4; ++ks) {
                        const float* p0 = e_f32 + (size_t)rowN0 * 128 + ks * 32 + g * 8;
                        const float* p1 = e_f32 + (size_t)rowN1 * 128 + ks * 32 + g * 8;
                        be[ks][0] = cvt8(*(const f32x4*)p0, *(const f32x4*)(p0 + 4));
                        be[ks][1] = cvt8(*(const f32x4*)p1, *(const f32x4*)(p1 + 4));
                    }
                } else {
                    #pragma unroll
                    for (int ks = 0; ks < 4; ++ks) {
                        be[ks][0] = *(const bf16x8*)(e_b16 + (size_t)rowN0 * 128 + ks * 32 + g * 8);
                        be[ks][1] = *(const bf16x8*)(e_b16 + (size_t)rowN1 * 128 + ks * 32 + g * 8);
                    }
                }
            }
            if (p == 4 && more) {               // bs dead after p==3
                #pragma unroll
                for (int ks = 0; ks < 4; ++ks) {
                    bs[ks][0] = *(const bf16x8*)(v_bf + (size_t)sN0 * 128 + ks * 32 + g * 8);
                    bs[ks][1] = *(const bf16x8*)(v_bf + (size_t)sN1 * 128 + ks * 32 + g * 8);
                }
            }
            if (p == 6 && more) {               // br dead after p==5
                #pragma unroll
                for (int ks = 0; ks < 4; ++ks) {
                    br[ks][0] = *(const bf16x8*)(v_bf + (size_t)rN0 * 128 + ks * 32 + g * 8);
                    br[ks][1] = *(const bf16x8*)(v_bf + (size_t)rN1 * 128 + ks * 32 + g * 8);
                }
            }
            if (p < 7) STAGE_WRITE2(wl[cur ^ 1]);
            else if (more) STAGE_WRITE2(wl[cur ^ 1]);   // cur=1 -> wl[0] for next tile
            __syncthreads();
        }

        // epilogue2: e_new = e_old + out + b2 (e_old rows L2-warm)
        #pragma unroll
        for (int mt = 0; mt < 2; ++mt) {
            const size_t r = (mt == 0) ? (size_t)row0 : (size_t)row1;
            f32x4 eof[8]; bf16x4 eob[8];
            #pragma unroll
            for (int oc = 0; oc < 8; ++oc) {
                const int col = oc * 16 + g * 4;
                if (EF32) eof[oc] = *(const f32x4*)(e_f32 + r * 128 + col);
                else      eob[oc] = *(const bf16x4*)(e_b16 + r * 128 + col);
            }
            #pragma unroll
            for (int oc = 0; oc < 8; ++oc) {
                const int col = oc * 16 + g * 4;
                f32x4 b2v = *(const f32x4*)(b2 + col);
                bf16x4 stv;
                #pragma unroll
                for (int j = 0; j < 4; ++j) {
                    float eo = EF32 ? eof[oc][j] : (float)eob[oc][j];
                    stv[j] = (bf16)(eo + acc2[oc][mt][j] + b2v[j]);
                }
                __builtin_nontemporal_store(stv, (bf16x4*)(e_out + r * 128 + col));
            }
        }

        row0 = rowN0; row1 = rowN1;
    }
}

// ---------------------------------------------------------------------------
// node / unpool: exact round-5/12 double-buffered staging versions (frozen).
// ---------------------------------------------------------------------------
#define STAGE_LOAD(wp, st0, st1) do { \
    st0 = *(const bf16x8*)((wp) + tid * 8); \
    st1 = *(const bf16x8*)((wp) + 2048 + tid * 8); } while (0)
#define STAGE_WRITE(buf, st0, st1) do { \
    *(bf16x8*)&(buf)[tid >> 2][(tid & 3) * 8] = st0; \
    *(bf16x8*)&(buf)[(tid + 256) >> 2][(tid & 3) * 8] = st1; } while (0)

__global__ __launch_bounds__(256, 2)
void node_kernel(float* __restrict__ v_io,
                 bf16* __restrict__ v_bf,
                 const bf16* __restrict__ agg,
                 const bf16* __restrict__ w1s,      // [8][128][32]
                 const float* __restrict__ b1,
                 const bf16* __restrict__ w2s,      // [4][128][32]
                 const float* __restrict__ b2)
{
    const int tid = threadIdx.x;
    const int wv = tid >> 6, lane = tid & 63;
    const int lr = lane & 15, g = lane >> 4;
    const int wbase = blockIdx.x * 128 + wv * 32;

    __shared__ bf16 wl[2][128][40];
    __shared__ bf16 hid_all[4][32][136];
    bf16 (*hid)[136] = hid_all[wv];

    int row[2];
    row[0] = wbase + lr; row[1] = wbase + 16 + lr;

    bf16x8 bv[4][2], ba[4][2];
    #pragma unroll
    for (int ks = 0; ks < 4; ++ks)
        #pragma unroll
        for (int mt = 0; mt < 2; ++mt)
            bv[ks][mt] = *(const bf16x8*)(v_bf + (size_t)row[mt] * 128 + ks * 32 + g * 8);
    #pragma unroll
    for (int ks = 0; ks < 4; ++ks)
        #pragma unroll
        for (int mt = 0; mt < 2; ++mt)
            ba[ks][mt] = *(const bf16x8*)(agg + (size_t)row[mt] * 128 + ks * 32 + g * 8);

    bf16x8 st0, st1;
    STAGE_LOAD(w1s, st0, st1);
    STAGE_WRITE(wl[0], st0, st1);
    __syncthreads();

    f32x4 acc1[8][2], acc2[8][2], vo[8][2];
    #pragma unroll
    for (int oc = 0; oc < 8; ++oc) {
        f32x4 z = {0.f, 0.f, 0.f, 0.f};
        acc1[oc][0] = z; acc1[oc][1] = z;
    }

    #pragma unroll
    for (int s = 0; s < 12; ++s) {
        const int cur = s & 1;
        if (s < 11) {
            const bf16* wp = (s + 1 < 8) ? w1s + (size_t)(s + 1) * 4096
                                         : w2s + (size_t)(s + 1 - 8) * 4096;
            STAGE_LOAD(wp, st0, st1);
        }
        if (s == 8) {
            #pragma unroll
            for (int mt = 0; mt < 2; ++mt)
                #pragma unroll
                for (int oc = 0; oc < 8; ++oc)
                    vo[oc][mt] = *(const f32x4*)(v_io + (size_t)row[mt] * 128 + oc * 16 + g * 4);
        }
        bf16x8 a[8];
        #pragma unroll
        for (int oc = 0; oc < 8; ++oc)
            a[oc] = *(const bf16x8*)&wl[cur][oc * 16 + lr][g * 8];

        if (s < 8) {
            bf16x8 b0 = (s < 4) ? bv[s][0] : ba[s - 4][0];
            bf16x8 b1f = (s < 4) ? bv[s][1] : ba[s - 4][1];
            #pragma unroll
            for (int oc = 0; oc < 8; ++oc) {
                acc1[oc][0] = __builtin_amdgcn_mfma_f32_16x16x32_bf16(a[oc], b0, acc1[oc][0], 0, 0, 0);
                acc1[oc][1] = __builtin_amdgcn_mfma_f32_16x16x32_bf16(a[oc], b1f, acc1[oc][1], 0, 0, 0);
            }
        } else {
            if (s == 8) {
                #pragma unroll
                for (int oc = 0; oc < 8; ++oc) {
                    f32x4 z = {0.f, 0.f, 0.f, 0.f};
                    acc2[oc][0] = z; acc2[oc][1] = z;
                }
            }
            bf16x8 h0 = *(const bf16x8*)&hid[lr][(s - 8) * 32 + g * 8];
            bf16x8 h1 = *(const bf16x8*)&hid[16 + lr][(s - 8) * 32 + g * 8];
            #pragma unroll
            for (int oc = 0; oc < 8; ++oc) {
                acc2[oc][0] = __builtin_amdgcn_mfma_f32_16x16x32_bf16(a[oc], h0, acc2[oc][0], 0, 0, 0);
                acc2[oc][1] = __builtin_amdgcn_mfma_f32_16x16x32_bf16(a[oc], h1, acc2[oc][1], 0, 0, 0);
            }
        }
        if (s == 7) {
            #pragma unroll
            for (int mt = 0; mt < 2; ++mt)
                #pragma unroll
                for (int oc = 0; oc < 8; ++oc) {
                    const int col = oc * 16 + g * 4;
                    f32x4 bvv = *(const f32x4*)(b1 + col);
                    bf16x4 h;
                    #pragma unroll
                    for (int j = 0; j < 4; ++j)
                        h[j] = (bf16)selu_f(acc1[oc][mt][j] + bvv[j]);
                    *(bf16x4*)&hid[mt * 16 + lr][col] = h;
                }
        }
        if (s < 11) STAGE_WRITE(wl[cur ^ 1], st0, st1);
        __syncthreads();
    }

    #pragma unroll
    for (int mt = 0; mt < 2; ++mt) {
        const size_t r = row[mt];
        #pragma unroll
        for (int oc = 0; oc < 8; ++oc) {
            const int col = oc * 16 + g * 4;
            f32x4 b2v = *(const f32x4*)(b2 + col);
            f32x4 vn; bf16x4 m;
            #pragma unroll
            for (int j = 0; j < 4; ++j) {
                vn[j] = vo[oc][mt][j] + acc2[oc][mt][j] + b2v[j];
                m[j] = (bf16)vn[j];
            }
            *(f32x4*)(v_io + r * 128 + col) = vn;
            *(bf16x4*)(v_bf + r * 128 + col) = m;
        }
    }
}

__global__ __launch_bounds__(256, 2)
void unpool_kernel(const float* __restrict__ v_coarse,
                   const float* __restrict__ c_skip,
                   const float* __restrict__ rel_pos,
                   const float* __restrict__ uw1,    // fp32 [129][128], row 128 = rel row
                   const float* __restrict__ b1,
                   const bf16* __restrict__ w1s,     // [4][128][32]
                   const bf16* __restrict__ w2s,     // [4][128][32]
                   const float* __restrict__ b2,
                   const int* __restrict__ cluster,
                   float* __restrict__ v_out,
                   bf16* __restrict__ v_bf)
{
    const int tid = threadIdx.x;
    const int wv = tid >> 6, lane = tid & 63;
    const int lr = lane & 15, g = lane >> 4;
    const int wbase = blockIdx.x * 128 + wv * 32;

    __shared__ bf16 wl[2][128][40];
    __shared__ bf16 hid_all[4][32][136];
    bf16 (*hid)[136] = hid_all[wv];

    int row[2], cl[2]; float relv[2];
    #pragma unroll
    for (int mt = 0; mt < 2; ++mt) {
        row[mt] = wbase + mt * 16 + lr;
        cl[mt] = cluster[row[mt]];
        relv[mt] = rel_pos[row[mt]];
    }

    bf16x8 bfr[4][2];
    {
        f32x4 tlo[4][2], thi[4][2];
        #pragma unroll
        for (int ks = 0; ks < 4; ++ks)
            #pragma unroll
            for (int mt = 0; mt < 2; ++mt) {
                const float* p = v_coarse + (size_t)cl[mt] * 128 + ks * 32 + g * 8;
                tlo[ks][mt] = *(const f32x4*)p;
                thi[ks][mt] = *(const f32x4*)(p + 4);
            }
        #pragma unroll
        for (int ks = 0; ks < 4; ++ks)
            #pragma unroll
            for (int mt = 0; mt < 2; ++mt)
                bfr[ks][mt] = cvt8(tlo[ks][mt], thi[ks][mt]);
    }

    bf16x8 st0, st1;
    STAGE_LOAD(w1s, st0, st1);
    STAGE_WRITE(wl[0], st0, st1);
    __syncthreads();

    f32x4 acc1[8][2], acc2[8][2], cs[8][2];
    #pragma unroll
    for (int oc = 0; oc < 8; ++oc) {
        f32x4 z = {0.f, 0.f, 0.f, 0.f};
        acc1[oc][0] = z; acc1[oc][1] = z;
    }

    #pragma unroll
    for (int s = 0; s < 8; ++s) {
        const int cur = s & 1;
        if (s < 7) {
            const bf16* wp = (s + 1 < 4) ? w1s + (size_t)(s + 1) * 4096
                                         : w2s + (size_t)(s + 1 - 4) * 4096;
            STAGE_LOAD(wp, st0, st1);
        }
        if (s == 4) {
            #pragma unroll
            for (int mt = 0; mt < 2; ++mt)
                #pragma unroll
                for (int oc = 0; oc < 8; ++oc)
                    cs[oc][mt] = *(const f32x4*)(c_skip + (size_t)row[mt] * 128 + oc * 16 + g * 4);
        }
        bf16x8 a[8];
        #pragma unroll
        for (int oc = 0; oc < 8; ++oc)
            a[oc] = *(const bf16x8*)&wl[cur][oc * 16 + lr][g * 8];

        if (s < 4) {
            #pragma unroll
            for (int oc = 0; oc < 8; ++oc) {
                acc1[oc][0] = __builtin_amdgcn_mfma_f32_16x16x32_bf16(a[oc], bfr[s][0], acc1[oc][0], 0, 0, 0);
                acc1[oc][1] = __builtin_amdgcn_mfma_f32_16x16x32_bf16(a[oc], bfr[s][1], acc1[oc][1], 0, 0, 0);
            }
        } else {
            if (s == 4) {
                #pragma unroll
                for (int oc = 0; oc < 8; ++oc) {
                    f32x4 z = {0.f, 0.f, 0.f, 0.f};
                    acc2[oc][0] = z; acc2[oc][1] = z;
                }
            }
            bf16x8 h0 = *(const bf16x8*)&hid[lr][(s - 4) * 32 + g * 8];
            bf16x8 h1 = *(const bf16x8*)&hid[16 + lr][(s - 4) * 32 + g * 8];
            #pragma unroll
            for (int oc = 0; oc < 8; ++oc) {
                acc2[oc][0] = __builtin_amdgcn_mfma_f32_16x16x32_bf16(a[oc], h0, acc2[oc][0], 0, 0, 0);
                acc2[oc][1] = __builtin_amdgcn_mfma_f32_16x16x32_bf16(a[oc], h1, acc2[oc][1], 0, 0, 0);
            }
        }
        if (s == 3) {
            #pragma unroll
            for (int mt = 0; mt < 2; ++mt)
                #pragma unroll
                for (int oc = 0; oc < 8; ++oc) {
                    const int col = oc * 16 + g * 4;
                    f32x4 bvv = *(const f32x4*)(b1 + col);
                    f32x4 wlr = *(const f32x4*)(uw1 + 128 * 128 + col);
                    bf16x4 h;
                    #pragma unroll
                    for (int j = 0; j < 4; ++j)
                        h[j] = (bf16)selu_f(acc1[oc][mt][j] + bvv[j] + relv[mt] * wlr[j]);
                    *(bf16x4*)&hid[mt * 16 + lr][col] = h;
                }
        }
        if (s < 7) STAGE_WRITE(wl[cur ^ 1], st0, st1);
        __syncthreads();
    }

    #pragma unroll
    for (int mt = 0; mt < 2; ++mt) {
        const size_t r = row[mt];
        #pragma unroll
        for (int oc = 0; oc < 8; ++oc) {
            const int col = oc * 16 + g * 4;
            f32x4 b2v = *(const f32x4*)(b2 + col);
            f32x4 vn; bf16x4 m;
            #pragma unroll
            for (int j = 0; j < 4; ++j) {
                vn[j] = acc2[oc][mt][j] + b2v[j] + cs[oc][mt][j];
                m[j] = (bf16)vn[j];
            }
            *(f32x4*)(v_out + r * 128 + col) = vn;
            *(bf16x4*)(v_bf + r * 128 + col) = m;
        }
    }
}

extern "C" void kernel_launch(void* const* d_in, const int* in_sizes, int n_in,
                              void* d_out, int out_size, void* d_ws, size_t ws_size,
                              hipStream_t stream) {
    const float* v_c    = (const float*)d_in[0];
    const float* c_skip = (const float*)d_in[1];
    const float* e_skip = (const float*)d_in[2];
    const float* rel    = (const float*)d_in[3];
    const float* uw1    = (const float*)d_in[4];
    const float* ub1    = (const float*)d_in[5];
    const float* uw2    = (const float*)d_in[6];
    const float* ub2    = (const float*)d_in[7];
    const float* ew1    = (const float*)d_in[8];
    const float* eb1    = (const float*)d_in[9];
    const float* ew2    = (const float*)d_in[10];
    const float* eb2    = (const float*)d_in[11];
    const float* nw1    = (const float*)d_in[12];
    const float* nb1    = (const float*)d_in[13];
    const float* nw2    = (const float*)d_in[14];
    const float* nb2    = (const float*)d_in[15];
    const int*   ei     = (const int*)d_in[16];
    const int*   clus   = (const int*)d_in[17];

    char* ws = (char*)d_ws;
    bf16*  e_bf   = (bf16*)(ws);                      // 100,663,296 B
    bf16*  v_bf   = (bf16*)(ws + 100663296);          //  16,777,216 B
    bf16*  agg    = (bf16*)(ws + 117440512);          //  16,777,216 B
    bf16*  wb     = (bf16*)(ws + 134217728);          //     524,288 B
    int*   cnt    = (int*) (ws + 134742016);          //     262,144 B
    int*   rowptr = (int*) (ws + 135004160);          //     262,148 B
    int*   cursor = (int*) (ws + 135266308);          //     262,144 B
    int*   perm   = (int*) (ws + 135528452);          //   1,572,864 B

    float* vout = (float*)d_out;

    prep_weights<<<1024, 256, 0, stream>>>(uw1, uw2, ew1, ew2, nw1, nw2, wb);
    hipMemsetAsync(cnt, 0, 262144, stream);
    hist_kernel<<<1536, 256, 0, stream>>>(ei, cnt);
    scan_kernel<<<1, 1024, 0, stream>>>(cnt, rowptr, cursor);
    scatter_kernel<<<1536, 256, 0, stream>>>(ei, cursor, perm);

    unpool_kernel<<<512, 256, 0, stream>>>(v_c, c_skip, rel, uw1, ub1,
                                           wb + 0, wb + 16384, ub2, clus, vout, v_bf);

    // layer 0
    edge_kernel<true><<<512, 256, 0, stream>>>((const void*)e_skip, e_bf, v_bf, ei,
                                               wb + 32768, eb1, wb + 131072, eb2);
    agg_kernel<<<2048, 256, 0, stream>>>(e_bf, rowptr, perm, agg);
    node_kernel<<<512, 256, 0, stream>>>(vout, v_bf, agg,
                                         wb + 163840, nb1, wb + 229376, nb2);

    // layer 1
    edge_kernel<false><<<512, 256, 0, stream>>>((const void*)e_bf, e_bf, v_bf, ei,
                                                wb + 32768 + 49152, eb1 + 128,
                                                wb + 131072 + 16384, eb2 + 128);
    agg_kernel<<<2048, 256, 0, stream>>>(e_bf, rowptr, perm, agg);
    node_kernel<<<512, 256, 0, stream>>>(vout, v_bf, agg,
                                         wb + 163840 + 32768, nb1 + 128, wb + 229376 + 16384, nb2 + 128);
}

// Round 17
// 518.026 us; speedup vs baseline: 1.3518x; 1.3518x over previous
//
#include <hip/hip_runtime.h>
#include <hip/hip_bf16.h>
#include <stdint.h>

#define NCOARSE 16384
#define NFINE   65536
#define NEDGE   393216

typedef __bf16 bf16;
typedef bf16 bf16x8 __attribute__((ext_vector_type(8)));
typedef bf16 bf16x4 __attribute__((ext_vector_type(4)));
typedef float f32x4 __attribute__((ext_vector_type(4)));

__device__ __forceinline__ float selu_f(float x) {
    return x > 0.f ? 1.0507009873554805f * x
                   : 1.7580993408473766f * (__expf(x) - 1.f);
}

__device__ __forceinline__ bf16x8 cvt8(f32x4 lo, f32x4 hi) {
    bf16x8 r;
    r[0] = (bf16)lo[0]; r[1] = (bf16)lo[1]; r[2] = (bf16)lo[2]; r[3] = (bf16)lo[3];
    r[4] = (bf16)hi[0]; r[5] = (bf16)hi[1]; r[6] = (bf16)hi[2]; r[7] = (bf16)hi[3];
    return r;
}

// ---------------------------------------------------------------------------
// Weight prep: seg-major bf16 layout  w[seg][128 n][32 k]  (seg = k/32).
// Region offsets (elems): uw1=0, uw2=16384, ew1=32768(+l*49152),
//   ew2=131072(+l*16384), nw1=163840(+l*32768), nw2=229376(+l*16384)
// ---------------------------------------------------------------------------
__global__ void prep_weights(const float* __restrict__ uw1, const float* __restrict__ uw2,
                             const float* __restrict__ ew1, const float* __restrict__ ew2,
                             const float* __restrict__ nw1, const float* __restrict__ nw2,
                             bf16* __restrict__ wb)
{
    int i = blockIdx.x * 256 + threadIdx.x;   // 0..262143, exact
    float v;
    if (i < 16384) {                    // unpool_w1 [128k][128n]
        int j = i; int k = (j >> 12) * 32 + (j & 31), n = (j & 4095) >> 5;
        v = uw1[k * 128 + n];
    } else if (i < 32768) {             // unpool_w2
        int j = i - 16384; int k = (j >> 12) * 32 + (j & 31), n = (j & 4095) >> 5;
        v = uw2[k * 128 + n];
    } else if (i < 131072) {            // edge_w1 [2][384k][128n]
        int j = i - 32768; int l = j / 49152; j -= l * 49152;
        int k = (j >> 12) * 32 + (j & 31), n = (j & 4095) >> 5;
        v = ew1[l * 49152 + k * 128 + n];
    } else if (i < 163840) {            // edge_w2 [2][128][128]
        int j = i - 131072; int l = j >> 14; j &= 16383;
        int k = (j >> 12) * 32 + (j & 31), n = (j & 4095) >> 5;
        v = ew2[l * 16384 + k * 128 + n];
    } else if (i < 229376) {            // node_w1 [2][256k][128n]
        int j = i - 163840; int l = j >> 15; j &= 32767;
        int k = (j >> 12) * 32 + (j & 31), n = (j & 4095) >> 5;
        v = nw1[l * 32768 + k * 128 + n];
    } else {                            // node_w2 [2][128][128]
        int j = i - 229376; int l = j >> 14; j &= 16383;
        int k = (j >> 12) * 32 + (j & 31), n = (j & 4095) >> 5;
        v = nw2[l * 16384 + k * 128 + n];
    }
    wb[i] = (bf16)v;
}

// ---------------------------------------------------------------------------
// CSR build (feeds ONLY the agg kernel).
// ---------------------------------------------------------------------------
__global__ void hist_kernel(const int* __restrict__ ei, int* __restrict__ cnt) {
    int e = blockIdx.x * 256 + threadIdx.x;
    if (e < NEDGE) atomicAdd(&cnt[ei[NEDGE + e]], 1);
}

__global__ __launch_bounds__(1024)
void scan_kernel(const int* __restrict__ cnt, int* __restrict__ rowptr,
                 int* __restrict__ cursor) {
    __shared__ int part[1024];
    const int t = threadIdx.x;
    const int base = t * 64;
    int s = 0;
    for (int i = 0; i < 64; ++i) s += cnt[base + i];
    part[t] = s;
    __syncthreads();
    for (int off = 1; off < 1024; off <<= 1) {
        int v = (t >= off) ? part[t - off] : 0;
        __syncthreads();
        part[t] += v;
        __syncthreads();
    }
    int run = part[t] - s;
    for (int i = 0; i < 64; ++i) {
        int c = cnt[base + i];
        rowptr[base + i] = run;
        cursor[base + i] = run;
        run += c;
    }
    if (t == 1023) rowptr[65536] = run;
}

__global__ void scatter_kernel(const int* __restrict__ ei, int* __restrict__ cursor,
                               int* __restrict__ perm) {
    int e = blockIdx.x * 256 + threadIdx.x;
    if (e < NEDGE) {
        int r = ei[NEDGE + e];
        int p = atomicAdd(&cursor[r], 1);
        perm[p] = e;
    }
}

__global__ __launch_bounds__(256)
void agg_kernel(const bf16* __restrict__ e, const int* __restrict__ rowptr,
                const int* __restrict__ perm, bf16* __restrict__ agg) {
    int t = blockIdx.x * 256 + threadIdx.x;     // 524288 total
    int node = t >> 3, c0 = (t & 7) * 16;
    int s = rowptr[node], en = rowptr[node + 1];
    float acc[16];
    #pragma unroll
    for (int k = 0; k < 16; ++k) acc[k] = 0.f;
    for (int j = s; j < en; ++j) {
        size_t ed = (size_t)perm[j];
        bf16x8 x0 = *(const bf16x8*)(e + ed * 128 + c0);
        bf16x8 x1 = *(const bf16x8*)(e + ed * 128 + c0 + 8);
        #pragma unroll
        for (int k = 0; k < 8; ++k) { acc[k] += (float)x0[k]; acc[8 + k] += (float)x1[k]; }
    }
    bf16x8 o0, o1;
    #pragma unroll
    for (int k = 0; k < 8; ++k) { o0[k] = (bf16)acc[k]; o1[k] = (bf16)acc[8 + k]; }
    *(bf16x8*)(agg + (size_t)node * 128 + c0) = o0;
    *(bf16x8*)(agg + (size_t)node * 128 + c0 + 8) = o1;
}

// ---------------------------------------------------------------------------
// Edge kernel (r12: 2 K-segments per barrier): 256 thr = 4 waves, wave owns
// 32 rows. Weights staged as PAIRS of K=32 segs in double-buffered LDS ->
// 8 steps + prologue = 9 barriers. 2 blocks/CU (proven occupancy optimum;
// 1/3/4 blocks, 384/512-thr, multi-tile, P-hoist all measured worse).
// LDS 40,960 + 34,816 = 75,776 B/block.
// ---------------------------------------------------------------------------
#define STAGE_LOAD2(wp0, wp1) do { \
    st0 = *(const bf16x8*)((wp0) + tid * 8); \
    st1 = *(const bf16x8*)((wp0) + 2048 + tid * 8); \
    st2 = *(const bf16x8*)((wp1) + tid * 8); \
    st3 = *(const bf16x8*)((wp1) + 2048 + tid * 8); } while (0)
#define STAGE_WRITE2(buf) do { \
    *(bf16x8*)&(buf)[0][tid >> 2][(tid & 3) * 8] = st0; \
    *(bf16x8*)&(buf)[0][(tid + 256) >> 2][(tid & 3) * 8] = st1; \
    *(bf16x8*)&(buf)[1][tid >> 2][(tid & 3) * 8] = st2; \
    *(bf16x8*)&(buf)[1][(tid + 256) >> 2][(tid & 3) * 8] = st3; } while (0)

template<bool EF32>
__global__ __launch_bounds__(256, 2)
void edge_kernel(const void* __restrict__ e_in_v,   // fp32 e_skip (L0) or bf16 e (L1)
                 bf16* __restrict__ e_out,
                 const bf16* __restrict__ v_bf,
                 const int* __restrict__ ei,        // [2][NEDGE]
                 const bf16* __restrict__ w1s,      // seg-major [12][128][32]
                 const float* __restrict__ b1,
                 const bf16* __restrict__ w2s,      // seg-major [4][128][32]
                 const float* __restrict__ b2)
{
    const int tid = threadIdx.x;
    const int wv = tid >> 6, lane = tid & 63;
    const int lr = lane & 15, g = lane >> 4;
    const int wbase = blockIdx.x * 128 + wv * 32;

    __shared__ bf16 wl[2][2][128][40];         // 40,960 B (dbuf x segpair)
    __shared__ bf16 hid_all[4][32][136];       // 34,816 B
    bf16 (*hid)[136] = hid_all[wv];

    const float* e_f32 = (const float*)e_in_v;
    const bf16*  e_b16 = (const bf16*)e_in_v;

    int row[2], sidx[2], ridx[2];
    #pragma unroll
    for (int mt = 0; mt < 2; ++mt) {
        row[mt] = wbase + mt * 16 + lr;
        sidx[mt] = ei[row[mt]];
        ridx[mt] = ei[NEDGE + row[mt]];
    }

    // ---- B prefetch: all 24 gathers in flight ----
    bf16x8 be[4][2], bs[4][2], br[4][2];
    #pragma unroll
    for (int ks = 0; ks < 4; ++ks)
        #pragma unroll
        for (int mt = 0; mt < 2; ++mt)
            bs[ks][mt] = *(const bf16x8*)(v_bf + (size_t)sidx[mt] * 128 + ks * 32 + g * 8);
    #pragma unroll
    for (int ks = 0; ks < 4; ++ks)
        #pragma unroll
        for (int mt = 0; mt < 2; ++mt)
            br[ks][mt] = *(const bf16x8*)(v_bf + (size_t)ridx[mt] * 128 + ks * 32 + g * 8);
    if (EF32) {
        f32x4 tlo[4][2], thi[4][2];
        #pragma unroll
        for (int ks = 0; ks < 4; ++ks)
            #pragma unroll
            for (int mt = 0; mt < 2; ++mt) {
                const float* p = e_f32 + (size_t)row[mt] * 128 + ks * 32 + g * 8;
                tlo[ks][mt] = *(const f32x4*)p;
                thi[ks][mt] = *(const f32x4*)(p + 4);
            }
        #pragma unroll
        for (int ks = 0; ks < 4; ++ks)
            #pragma unroll
            for (int mt = 0; mt < 2; ++mt)
                be[ks][mt] = cvt8(tlo[ks][mt], thi[ks][mt]);
    } else {
        #pragma unroll
        for (int ks = 0; ks < 4; ++ks)
            #pragma unroll
            for (int mt = 0; mt < 2; ++mt)
                be[ks][mt] = *(const bf16x8*)(e_b16 + (size_t)row[mt] * 128 + ks * 32 + g * 8);
    }

    // ---- prologue: stage seg pair {0,1} ----
    bf16x8 st0, st1, st2, st3;
    STAGE_LOAD2(w1s, w1s + 4096);
    STAGE_WRITE2(wl[0]);
    __syncthreads();

    f32x4 acc1[8][2], acc2[8][2];
    #pragma unroll
    for (int oc = 0; oc < 8; ++oc) {
        f32x4 z = {0.f, 0.f, 0.f, 0.f};
        acc1[oc][0] = z; acc1[oc][1] = z;
    }

    f32x4  eof[8][2];
    bf16x4 eob[8][2];

    // 8 steps; step p consumes seg pair {2p, 2p+1}; segs 0-11 = GEMM1, 12-15 = GEMM2
    #pragma unroll
    for (int p = 0; p < 8; ++p) {
        const int cur = p & 1;
        if (p < 7) {
            const int s0n = 2 * p + 2, s1n = 2 * p + 3;
            const bf16* wp0 = (s0n < 12) ? w1s + (size_t)s0n * 4096 : w2s + (size_t)(s0n - 12) * 4096;
            const bf16* wp1 = (s1n < 12) ? w1s + (size_t)s1n * 4096 : w2s + (size_t)(s1n - 12) * 4096;
            STAGE_LOAD2(wp0, wp1);
        }
        if (p == 6) {  // issue e_old loads (land by epilogue2)
            #pragma unroll
            for (int mt = 0; mt < 2; ++mt)
                #pragma unroll
                for (int oc = 0; oc < 8; ++oc) {
                    const int col = oc * 16 + g * 4;
                    if (EF32) eof[oc][mt] = *(const f32x4*)(e_f32 + (size_t)row[mt] * 128 + col);
                    else      eob[oc][mt] = *(const bf16x4*)(e_b16 + (size_t)row[mt] * 128 + col);
                }
        }
        // A-fragments for both segs of the pair
        bf16x8 a0[8], a1[8];
        #pragma unroll
        for (int oc = 0; oc < 8; ++oc) {
            a0[oc] = *(const bf16x8*)&wl[cur][0][oc * 16 + lr][g * 8];
            a1[oc] = *(const bf16x8*)&wl[cur][1][oc * 16 + lr][g * 8];
        }

        if (p < 6) {
            const int s0 = 2 * p, s1 = 2 * p + 1;
            bf16x8 b00 = (s0 < 4) ? be[s0][0] : (s0 < 8) ? bs[s0 - 4][0] : br[s0 - 8][0];
            bf16x8 b01 = (s0 < 4) ? be[s0][1] : (s0 < 8) ? bs[s0 - 4][1] : br[s0 - 8][1];
            bf16x8 b10 = (s1 < 4) ? be[s1][0] : (s1 < 8) ? bs[s1 - 4][0] : br[s1 - 8][0];
            bf16x8 b11 = (s1 < 4) ? be[s1][1] : (s1 < 8) ? bs[s1 - 4][1] : br[s1 - 8][1];
            #pragma unroll
            for (int oc = 0; oc < 8; ++oc) {
                acc1[oc][0] = __builtin_amdgcn_mfma_f32_16x16x32_bf16(a0[oc], b00, acc1[oc][0], 0, 0, 0);
                acc1[oc][1] = __builtin_amdgcn_mfma_f32_16x16x32_bf16(a0[oc], b01, acc1[oc][1], 0, 0, 0);
            }
            #pragma unroll
            for (int oc = 0; oc < 8; ++oc) {
                acc1[oc][0] = __builtin_amdgcn_mfma_f32_16x16x32_bf16(a1[oc], b10, acc1[oc][0], 0, 0, 0);
                acc1[oc][1] = __builtin_amdgcn_mfma_f32_16x16x32_bf16(a1[oc], b11, acc1[oc][1], 0, 0, 0);
            }
        } else {
            if (p == 6) {
                #pragma unroll
                for (int oc = 0; oc < 8; ++oc) {
                    f32x4 z = {0.f, 0.f, 0.f, 0.f};
                    acc2[oc][0] = z; acc2[oc][1] = z;
                }
            }
            const int k2 = 2 * (p - 6);   // hid seg pair {k2, k2+1}
            bf16x8 h00 = *(const bf16x8*)&hid[lr][k2 * 32 + g * 8];
            bf16x8 h01 = *(const bf16x8*)&hid[16 + lr][k2 * 32 + g * 8];
            bf16x8 h10 = *(const bf16x8*)&hid[lr][(k2 + 1) * 32 + g * 8];
            bf16x8 h11 = *(const bf16x8*)&hid[16 + lr][(k2 + 1) * 32 + g * 8];
            #pragma unroll
            for (int oc = 0; oc < 8; ++oc) {
                acc2[oc][0] = __builtin_amdgcn_mfma_f32_16x16x32_bf16(a0[oc], h00, acc2[oc][0], 0, 0, 0);
                acc2[oc][1] = __builtin_amdgcn_mfma_f32_16x16x32_bf16(a0[oc], h01, acc2[oc][1], 0, 0, 0);
            }
            #pragma unroll
            for (int oc = 0; oc < 8; ++oc) {
                acc2[oc][0] = __builtin_amdgcn_mfma_f32_16x16x32_bf16(a1[oc], h10, acc2[oc][0], 0, 0, 0);
                acc2[oc][1] = __builtin_amdgcn_mfma_f32_16x16x32_bf16(a1[oc], h11, acc2[oc][1], 0, 0, 0);
            }
        }
        if (p == 5) {  // epilogue1: selu -> hid (both m-tiles); wave-private
            #pragma unroll
            for (int mt = 0; mt < 2; ++mt)
                #pragma unroll
                for (int oc = 0; oc < 8; ++oc) {
                    const int col = oc * 16 + g * 4;
                    f32x4 bv = *(const f32x4*)(b1 + col);
                    bf16x4 h;
                    #pragma unroll
                    for (int j = 0; j < 4; ++j)
                        h[j] = (bf16)selu_f(acc1[oc][mt][j] + bv[j]);
                    *(bf16x4*)&hid[mt * 16 + lr][col] = h;
                }
        }
        if (p < 7) STAGE_WRITE2(wl[cur ^ 1]);
        __syncthreads();
    }

    // epilogue2: e_new = e_old + out + b2
    #pragma unroll
    for (int mt = 0; mt < 2; ++mt) {
        const size_t r = row[mt];
        #pragma unroll
        for (int oc = 0; oc < 8; ++oc) {
            const int col = oc * 16 + g * 4;
            f32x4 b2v = *(const f32x4*)(b2 + col);
            bf16x4 stv;
            #pragma unroll
            for (int j = 0; j < 4; ++j) {
                float eo = EF32 ? eof[oc][mt][j] : (float)eob[oc][mt][j];
                stv[j] = (bf16)(eo + acc2[oc][mt][j] + b2v[j]);
            }
            __builtin_nontemporal_store(stv, (bf16x4*)(e_out + r * 128 + col));
        }
    }
}

// ---------------------------------------------------------------------------
// node / unpool: exact round-5 double-buffered staging versions.
// ---------------------------------------------------------------------------
#define STAGE_LOAD(wp, st0, st1) do { \
    st0 = *(const bf16x8*)((wp) + tid * 8); \
    st1 = *(const bf16x8*)((wp) + 2048 + tid * 8); } while (0)
#define STAGE_WRITE(buf, st0, st1) do { \
    *(bf16x8*)&(buf)[tid >> 2][(tid & 3) * 8] = st0; \
    *(bf16x8*)&(buf)[(tid + 256) >> 2][(tid & 3) * 8] = st1; } while (0)

__global__ __launch_bounds__(256, 2)
void node_kernel(float* __restrict__ v_io,
                 bf16* __restrict__ v_bf,
                 const bf16* __restrict__ agg,
                 const bf16* __restrict__ w1s,      // [8][128][32]
                 const float* __restrict__ b1,
                 const bf16* __restrict__ w2s,      // [4][128][32]
                 const float* __restrict__ b2)
{
    const int tid = threadIdx.x;
    const int wv = tid >> 6, lane = tid & 63;
    const int lr = lane & 15, g = lane >> 4;
    const int wbase = blockIdx.x * 128 + wv * 32;

    __shared__ bf16 wl[2][128][40];
    __shared__ bf16 hid_all[4][32][136];
    bf16 (*hid)[136] = hid_all[wv];

    int row[2];
    row[0] = wbase + lr; row[1] = wbase + 16 + lr;

    bf16x8 bv[4][2], ba[4][2];
    #pragma unroll
    for (int ks = 0; ks < 4; ++ks)
        #pragma unroll
        for (int mt = 0; mt < 2; ++mt)
            bv[ks][mt] = *(const bf16x8*)(v_bf + (size_t)row[mt] * 128 + ks * 32 + g * 8);
    #pragma unroll
    for (int ks = 0; ks < 4; ++ks)
        #pragma unroll
        for (int mt = 0; mt < 2; ++mt)
            ba[ks][mt] = *(const bf16x8*)(agg + (size_t)row[mt] * 128 + ks * 32 + g * 8);

    bf16x8 st0, st1;
    STAGE_LOAD(w1s, st0, st1);
    STAGE_WRITE(wl[0], st0, st1);
    __syncthreads();

    f32x4 acc1[8][2], acc2[8][2], vo[8][2];
    #pragma unroll
    for (int oc = 0; oc < 8; ++oc) {
        f32x4 z = {0.f, 0.f, 0.f, 0.f};
        acc1[oc][0] = z; acc1[oc][1] = z;
    }

    #pragma unroll
    for (int s = 0; s < 12; ++s) {
        const int cur = s & 1;
        if (s < 11) {
            const bf16* wp = (s + 1 < 8) ? w1s + (size_t)(s + 1) * 4096
                                         : w2s + (size_t)(s + 1 - 8) * 4096;
            STAGE_LOAD(wp, st0, st1);
        }
        if (s == 8) {
            #pragma unroll
            for (int mt = 0; mt < 2; ++mt)
                #pragma unroll
                for (int oc = 0; oc < 8; ++oc)
                    vo[oc][mt] = *(const f32x4*)(v_io + (size_t)row[mt] * 128 + oc * 16 + g * 4);
        }
        bf16x8 a[8];
        #pragma unroll
        for (int oc = 0; oc < 8; ++oc)
            a[oc] = *(const bf16x8*)&wl[cur][oc * 16 + lr][g * 8];

        if (s < 8) {
            bf16x8 b0 = (s < 4) ? bv[s][0] : ba[s - 4][0];
            bf16x8 b1f = (s < 4) ? bv[s][1] : ba[s - 4][1];
            #pragma unroll
            for (int oc = 0; oc < 8; ++oc) {
                acc1[oc][0] = __builtin_amdgcn_mfma_f32_16x16x32_bf16(a[oc], b0, acc1[oc][0], 0, 0, 0);
                acc1[oc][1] = __builtin_amdgcn_mfma_f32_16x16x32_bf16(a[oc], b1f, acc1[oc][1], 0, 0, 0);
            }
        } else {
            if (s == 8) {
                #pragma unroll
                for (int oc = 0; oc < 8; ++oc) {
                    f32x4 z = {0.f, 0.f, 0.f, 0.f};
                    acc2[oc][0] = z; acc2[oc][1] = z;
                }
            }
            bf16x8 h0 = *(const bf16x8*)&hid[lr][(s - 8) * 32 + g * 8];
            bf16x8 h1 = *(const bf16x8*)&hid[16 + lr][(s - 8) * 32 + g * 8];
            #pragma unroll
            for (int oc = 0; oc < 8; ++oc) {
                acc2[oc][0] = __builtin_amdgcn_mfma_f32_16x16x32_bf16(a[oc], h0, acc2[oc][0], 0, 0, 0);
                acc2[oc][1] = __builtin_amdgcn_mfma_f32_16x16x32_bf16(a[oc], h1, acc2[oc][1], 0, 0, 0);
            }
        }
        if (s == 7) {
            #pragma unroll
            for (int mt = 0; mt < 2; ++mt)
                #pragma unroll
                for (int oc = 0; oc < 8; ++oc) {
                    const int col = oc * 16 + g * 4;
                    f32x4 bvv = *(const f32x4*)(b1 + col);
                    bf16x4 h;
                    #pragma unroll
                    for (int j = 0; j < 4; ++j)
                        h[j] = (bf16)selu_f(acc1[oc][mt][j] + bvv[j]);
                    *(bf16x4*)&hid[mt * 16 + lr][col] = h;
                }
        }
        if (s < 11) STAGE_WRITE(wl[cur ^ 1], st0, st1);
        __syncthreads();
    }

    #pragma unroll
    for (int mt = 0; mt < 2; ++mt) {
        const size_t r = row[mt];
        #pragma unroll
        for (int oc = 0; oc < 8; ++oc) {
            const int col = oc * 16 + g * 4;
            f32x4 b2v = *(const f32x4*)(b2 + col);
            f32x4 vn; bf16x4 m;
            #pragma unroll
            for (int j = 0; j < 4; ++j) {
                vn[j] = vo[oc][mt][j] + acc2[oc][mt][j] + b2v[j];
                m[j] = (bf16)vn[j];
            }
            *(f32x4*)(v_io + r * 128 + col) = vn;
            *(bf16x4*)(v_bf + r * 128 + col) = m;
        }
    }
}

__global__ __launch_bounds__(256, 2)
void unpool_kernel(const float* __restrict__ v_coarse,
                   const float* __restrict__ c_skip,
                   const float* __restrict__ rel_pos,
                   const float* __restrict__ uw1,    // fp32 [129][128], row 128 = rel row
                   const float* __restrict__ b1,
                   const bf16* __restrict__ w1s,     // [4][128][32]
                   const bf16* __restrict__ w2s,     // [4][128][32]
                   const float* __restrict__ b2,
                   const int* __restrict__ cluster,
                   float* __restrict__ v_out,
                   bf16* __restrict__ v_bf)
{
    const int tid = threadIdx.x;
    const int wv = tid >> 6, lane = tid & 63;
    const int lr = lane & 15, g = lane >> 4;
    const int wbase = blockIdx.x * 128 + wv * 32;

    __shared__ bf16 wl[2][128][40];
    __shared__ bf16 hid_all[4][32][136];
    bf16 (*hid)[136] = hid_all[wv];

    int row[2], cl[2]; float relv[2];
    #pragma unroll
    for (int mt = 0; mt < 2; ++mt) {
        row[mt] = wbase + mt * 16 + lr;
        cl[mt] = cluster[row[mt]];
        relv[mt] = rel_pos[row[mt]];
    }

    bf16x8 bfr[4][2];
    {
        f32x4 tlo[4][2], thi[4][2];
        #pragma unroll
        for (int ks = 0; ks < 4; ++ks)
            #pragma unroll
            for (int mt = 0; mt < 2; ++mt) {
                const float* p = v_coarse + (size_t)cl[mt] * 128 + ks * 32 + g * 8;
                tlo[ks][mt] = *(const f32x4*)p;
                thi[ks][mt] = *(const f32x4*)(p + 4);
            }
        #pragma unroll
        for (int ks = 0; ks < 4; ++ks)
            #pragma unroll
            for (int mt = 0; mt < 2; ++mt)
                bfr[ks][mt] = cvt8(tlo[ks][mt], thi[ks][mt]);
    }

    bf16x8 st0, st1;
    STAGE_LOAD(w1s, st0, st1);
    STAGE_WRITE(wl[0], st0, st1);
    __syncthreads();

    f32x4 acc1[8][2], acc2[8][2], cs[8][2];
    #pragma unroll
    for (int oc = 0; oc < 8; ++oc) {
        f32x4 z = {0.f, 0.f, 0.f, 0.f};
        acc1[oc][0] = z; acc1[oc][1] = z;
    }

    #pragma unroll
    for (int s = 0; s < 8; ++s) {
        const int cur = s & 1;
        if (s < 7) {
            const bf16* wp = (s + 1 < 4) ? w1s + (size_t)(s + 1) * 4096
                                         : w2s + (size_t)(s + 1 - 4) * 4096;
            STAGE_LOAD(wp, st0, st1);
        }
        if (s == 4) {
            #pragma unroll
            for (int mt = 0; mt < 2; ++mt)
                #pragma unroll
                for (int oc = 0; oc < 8; ++oc)
                    cs[oc][mt] = *(const f32x4*)(c_skip + (size_t)row[mt] * 128 + oc * 16 + g * 4);
        }
        bf16x8 a[8];
        #pragma unroll
        for (int oc = 0; oc < 8; ++oc)
            a[oc] = *(const bf16x8*)&wl[cur][oc * 16 + lr][g * 8];

        if (s < 4) {
            #pragma unroll
            for (int oc = 0; oc < 8; ++oc) {
                acc1[oc][0] = __builtin_amdgcn_mfma_f32_16x16x32_bf16(a[oc], bfr[s][0], acc1[oc][0], 0, 0, 0);
                acc1[oc][1] = __builtin_amdgcn_mfma_f32_16x16x32_bf16(a[oc], bfr[s][1], acc1[oc][1], 0, 0, 0);
            }
        } else {
            if (s == 4) {
                #pragma unroll
                for (int oc = 0; oc < 8; ++oc) {
                    f32x4 z = {0.f, 0.f, 0.f, 0.f};
                    acc2[oc][0] = z; acc2[oc][1] = z;
                }
            }
            bf16x8 h0 = *(const bf16x8*)&hid[lr][(s - 4) * 32 + g * 8];
            bf16x8 h1 = *(const bf16x8*)&hid[16 + lr][(s - 4) * 32 + g * 8];
            #pragma unroll
            for (int oc = 0; oc < 8; ++oc) {
                acc2[oc][0] = __builtin_amdgcn_mfma_f32_16x16x32_bf16(a[oc], h0, acc2[oc][0], 0, 0, 0);
                acc2[oc][1] = __builtin_amdgcn_mfma_f32_16x16x32_bf16(a[oc], h1, acc2[oc][1], 0, 0, 0);
            }
        }
        if (s == 3) {
            #pragma unroll
            for (int mt = 0; mt < 2; ++mt)
                #pragma unroll
                for (int oc = 0; oc < 8; ++oc) {
                    const int col = oc * 16 + g * 4;
                    f32x4 bvv = *(const f32x4*)(b1 + col);
                    f32x4 wlr = *(const f32x4*)(uw1 + 128 * 128 + col);
                    bf16x4 h;
                    #pragma unroll
                    for (int j = 0; j < 4; ++j)
                        h[j] = (bf16)selu_f(acc1[oc][mt][j] + bvv[j] + relv[mt] * wlr[j]);
                    *(bf16x4*)&hid[mt * 16 + lr][col] = h;
                }
        }
        if (s < 7) STAGE_WRITE(wl[cur ^ 1], st0, st1);
        __syncthreads();
    }

    #pragma unroll
    for (int mt = 0; mt < 2; ++mt) {
        const size_t r = row[mt];
        #pragma unroll
        for (int oc = 0; oc < 8; ++oc) {
            const int col = oc * 16 + g * 4;
            f32x4 b2v = *(const f32x4*)(b2 + col);
            f32x4 vn; bf16x4 m;
            #pragma unroll
            for (int j = 0; j < 4; ++j) {
                vn[j] = acc2[oc][mt][j] + b2v[j] + cs[oc][mt][j];
                m[j] = (bf16)vn[j];
            }
            *(f32x4*)(v_out + r * 128 + col) = vn;
            *(bf16x4*)(v_bf + r * 128 + col) = m;
        }
    }
}

extern "C" void kernel_launch(void* const* d_in, const int* in_sizes, int n_in,
                              void* d_out, int out_size, void* d_ws, size_t ws_size,
                              hipStream_t stream) {
    const float* v_c    = (const float*)d_in[0];
    const float* c_skip = (const float*)d_in[1];
    const float* e_skip = (const float*)d_in[2];
    const float* rel    = (const float*)d_in[3];
    const float* uw1    = (const float*)d_in[4];
    const float* ub1    = (const float*)d_in[5];
    const float* uw2    = (const float*)d_in[6];
    const float* ub2    = (const float*)d_in[7];
    const float* ew1    = (const float*)d_in[8];
    const float* eb1    = (const float*)d_in[9];
    const float* ew2    = (const float*)d_in[10];
    const float* eb2    = (const float*)d_in[11];
    const float* nw1    = (const float*)d_in[12];
    const float* nb1    = (const float*)d_in[13];
    const float* nw2    = (const float*)d_in[14];
    const float* nb2    = (const float*)d_in[15];
    const int*   ei     = (const int*)d_in[16];
    const int*   clus   = (const int*)d_in[17];

    char* ws = (char*)d_ws;
    bf16*  e_bf   = (bf16*)(ws);                      // 100,663,296 B
    bf16*  v_bf   = (bf16*)(ws + 100663296);          //  16,777,216 B
    bf16*  agg    = (bf16*)(ws + 117440512);          //  16,777,216 B
    bf16*  wb     = (bf16*)(ws + 134217728);          //     524,288 B
    int*   cnt    = (int*) (ws + 134742016);          //     262,144 B
    int*   rowptr = (int*) (ws + 135004160);          //     262,148 B
    int*   cursor = (int*) (ws + 135266308);          //     262,144 B
    int*   perm   = (int*) (ws + 135528452);          //   1,572,864 B

    float* vout = (float*)d_out;

    prep_weights<<<1024, 256, 0, stream>>>(uw1, uw2, ew1, ew2, nw1, nw2, wb);
    hipMemsetAsync(cnt, 0, 262144, stream);
    hist_kernel<<<1536, 256, 0, stream>>>(ei, cnt);
    scan_kernel<<<1, 1024, 0, stream>>>(cnt, rowptr, cursor);
    scatter_kernel<<<1536, 256, 0, stream>>>(ei, cursor, perm);

    unpool_kernel<<<512, 256, 0, stream>>>(v_c, c_skip, rel, uw1, ub1,
                                           wb + 0, wb + 16384, ub2, clus, vout, v_bf);

    // layer 0
    edge_kernel<true><<<3072, 256, 0, stream>>>((const void*)e_skip, e_bf, v_bf, ei,
                                                wb + 32768, eb1, wb + 131072, eb2);
    agg_kernel<<<2048, 256, 0, stream>>>(e_bf, rowptr, perm, agg);
    node_kernel<<<512, 256, 0, stream>>>(vout, v_bf, agg,
                                         wb + 163840, nb1, wb + 229376, nb2);

    // layer 1
    edge_kernel<false><<<3072, 256, 0, stream>>>((const void*)e_bf, e_bf, v_bf, ei,
                                                 wb + 32768 + 49152, eb1 + 128,
                                                 wb + 131072 + 16384, eb2 + 128);
    agg_kernel<<<2048, 256, 0, stream>>>(e_bf, rowptr, perm, agg);
    node_kernel<<<512, 256, 0, stream>>>(vout, v_bf, agg,
                                         wb + 163840 + 32768, nb1 + 128, wb + 229376 + 16384, nb2 + 128);
}